// Round 17
// baseline (191.677 us; speedup 1.0000x reference)
//
#include <hip/hip_runtime.h>
#include <cstdint>
#include <cstddef>

#define NEG_SLOPE 0.2f
#define F_IN 128
#define C1 256      // HEADS*HID layer-1 width
#define HID 64
#define HEADS 4
#define LOG2E 1.4426950408889634f
#define NBUCK 392   // ceil(50000/128)
#define BCAP 5120   // per-bucket capacity (mean 4224, sigma ~65)

typedef __attribute__((ext_vector_type(8))) short bf16x8;
typedef __attribute__((ext_vector_type(4))) float f32x4;
typedef __attribute__((ext_vector_type(2))) float f32x2;
typedef unsigned long long ull;

__device__ __forceinline__ float wave_reduce_sum(float v) {
#pragma unroll
  for (int off = 32; off > 0; off >>= 1) v += __shfl_down(v, off);
  return v;
}

__device__ __forceinline__ unsigned short f2bf(float f) {
  union { float f; unsigned int u; } v; v.f = f;
  unsigned int u = v.u;
  unsigned int r = (u + 0x7fffu + ((u >> 16) & 1u)) >> 16;  // RNE
  return (unsigned short)r;
}

__device__ __forceinline__ unsigned char f2fp8(float f) {
  int p = __builtin_amdgcn_cvt_pk_fp8_f32(f, f, 0, false);  // OCP e4m3fn
  return (unsigned char)(p & 0xff);
}

// ---------------- setup: zero gcursor/poolrep + weight pre-pack (merged) --------
__global__ __launch_bounds__(256) void setup_kernel(const float* __restrict__ W1,
                                                    const float* __restrict__ W2,
                                                    unsigned short* __restrict__ W1b,
                                                    unsigned short* __restrict__ W2b,
                                                    int* __restrict__ gcursor,
                                                    float* __restrict__ poolrep) {
  const int TOT = 512 + 4096 + 32768 + 16384;
  for (int idx = threadIdx.x + blockIdx.x * 256; idx < TOT; idx += 256 * gridDim.x) {
    if (idx < 512) {
      gcursor[idx] = 0;
    } else if (idx < 512 + 4096) {
      poolrep[idx - 512] = 0.f;
    } else if (idx < 512 + 4096 + 32768) {
      int o = idx - (512 + 4096);
      int head = o >> 13, ks = (o >> 11) & 3, nt = (o >> 9) & 3;
      int lane = (o >> 3) & 63, j = o & 7;
      int k = ks * 32 + (lane >> 4) * 8 + j;
      int c = head * 64 + nt * 16 + (lane & 15);
      W1b[o] = f2bf(W1[k * 256 + c]);
    } else {
      int o = idx - (512 + 4096 + 32768);
      int ks = o >> 11, nt = (o >> 9) & 3, lane = (o >> 3) & 63, j = o & 7;
      int k = ks * 32 + (lane >> 4) * 8 + j;
      int c = nt * 16 + (lane & 15);
      W2b[o] = f2bf(W2[k * 64 + c]);
    }
  }
}

// ---------------- fat kernel: GEMM1 (blocks < rowblocks) + edge partition ------
__global__ __launch_bounds__(256) void gemm1_partition(const float* __restrict__ Af,
                                                       const unsigned short* __restrict__ Wb,
                                                       unsigned char* __restrict__ H8,
                                                       float* __restrict__ as_out,
                                                       float* __restrict__ ad_out,
                                                       const float* __restrict__ att_s,
                                                       const float* __restrict__ att_d,
                                                       int M, int rowblocks,
                                                       const int* __restrict__ esrc,
                                                       const int* __restrict__ edst,
                                                       int* __restrict__ gcursor,
                                                       unsigned* __restrict__ pairs,
                                                       int E, int Etot) {
  __shared__ int hist[512];
  __shared__ int base[512];
  if (blockIdx.x < rowblocks) {
    // ---- GEMM1: fp32 A -> bf16 MFMA, fp8 h-store, all heads ----
    constexpr int KSTEPS = 4, NH = HEADS, K = 128, N = 256;
    const int lane = threadIdx.x & 63, wid = threadIdx.x >> 6;
    const int rowbase = blockIdx.x * 64 + wid * 16;
    const int g = lane >> 4, li = lane & 15;
    int r_a = rowbase + li;
    if (r_a > M - 1) r_a = M - 1;

    f32x4 acc[NH][4];
#pragma unroll
    for (int h = 0; h < NH; h++)
#pragma unroll
      for (int nt = 0; nt < 4; nt++) {
        acc[h][nt][0] = 0.f; acc[h][nt][1] = 0.f; acc[h][nt][2] = 0.f; acc[h][nt][3] = 0.f;
      }

#pragma unroll
    for (int ks = 0; ks < KSTEPS; ks++) {
      bf16x8 a;
      const float* p = Af + (size_t)r_a * K + ks * 32 + g * 8;
      float4 v0 = *(const float4*)p, v1 = *(const float4*)(p + 4);
      a[0] = (short)f2bf(v0.x); a[1] = (short)f2bf(v0.y);
      a[2] = (short)f2bf(v0.z); a[3] = (short)f2bf(v0.w);
      a[4] = (short)f2bf(v1.x); a[5] = (short)f2bf(v1.y);
      a[6] = (short)f2bf(v1.z); a[7] = (short)f2bf(v1.w);
#pragma unroll
      for (int h = 0; h < NH; h++)
#pragma unroll
        for (int nt = 0; nt < 4; nt++) {
          bf16x8 b = *(const bf16x8*)(Wb + ((size_t)((h * KSTEPS + ks) * 4 + nt) * 64 + lane) * 8);
          acc[h][nt] = __builtin_amdgcn_mfma_f32_16x16x32_bf16(a, b, acc[h][nt], 0, 0, 0);
        }
    }

#pragma unroll
    for (int h = 0; h < NH; h++) {
      float asum[4] = {0.f, 0.f, 0.f, 0.f}, dsum[4] = {0.f, 0.f, 0.f, 0.f};
#pragma unroll
      for (int nt = 0; nt < 4; nt++) {
        float ws = att_s[h * 64 + nt * 16 + li];
        float wd = att_d[h * 64 + nt * 16 + li];
#pragma unroll
        for (int r = 0; r < 4; r++) { asum[r] += acc[h][nt][r] * ws; dsum[r] += acc[h][nt][r] * wd; }
      }
#pragma unroll
      for (int r = 0; r < 4; r++) {
#pragma unroll
        for (int m = 1; m < 16; m <<= 1) {
          asum[r] += __shfl_xor(asum[r], m);
          dsum[r] += __shfl_xor(dsum[r], m);
        }
      }
#pragma unroll
      for (int r = 0; r < 4; r++) {
        int gr = rowbase + g * 4 + r;
        if (gr < M) {
#pragma unroll
          for (int nt = 0; nt < 4; nt++)
            H8[(size_t)gr * N + h * 64 + nt * 16 + li] = f2fp8(acc[h][nt][r]);
          if (li == 0) {
            as_out[(size_t)gr * NH + h] = asum[r] * LOG2E;
            ad_out[(size_t)gr * NH + h] = dsum[r] * LOG2E;
          }
        }
      }
    }
  } else {
    // ---- partition: packed 4B pairs into 392 coarse buckets (dst>>7) ----
    const int tid = threadIdx.x;
    const int e0 = (blockIdx.x - rowblocks) * 2048;
    hist[tid] = 0; hist[tid + 256] = 0;
    __syncthreads();
    int d8[8], rk8[8], bk8[8];
#pragma unroll
    for (int j = 0; j < 8; j++) {
      int e = e0 + tid * 8 + j;
      d8[j] = -1;
      if (e < Etot) {
        int d = (e < E) ? edst[e] : (e - E);
        d8[j] = d;
        bk8[j] = d >> 7;
        rk8[j] = atomicAdd(&hist[bk8[j]], 1);
      }
    }
    __syncthreads();
    if (hist[tid] > 0) base[tid] = atomicAdd(&gcursor[tid], hist[tid]);
    if (hist[tid + 256] > 0) base[tid + 256] = atomicAdd(&gcursor[tid + 256], hist[tid + 256]);
    __syncthreads();
#pragma unroll
    for (int j = 0; j < 8; j++) {
      int e = e0 + tid * 8 + j;
      if (e < Etot) {
        int s = (e < E) ? esrc[e] : (e - E);
        pairs[(size_t)bk8[j] * BCAP + base[bk8[j]] + rk8[j]] =
            (unsigned)s | ((unsigned)(d8[j] & 127) << 16);
      }
    }
  }
}

// per-bucket CSR (128 dsts) + fused edge weights; computes its own bucket prefix.
__global__ __launch_bounds__(512) void bucket_csr(const unsigned* __restrict__ pairs,
                                                  const int* __restrict__ gcursor,
                                                  const float4* __restrict__ as1,
                                                  const float4* __restrict__ ad1,
                                                  unsigned short* __restrict__ src16,
                                                  ull* __restrict__ w4,
                                                  int* __restrict__ row_ptr,
                                                  int N, int Etot) {
  __shared__ int hist[128], offs[128], cnt2[128], gpre[512];
  const int b = blockIdx.x;
  const int tid = threadIdx.x;
  if (tid < 128) { hist[tid] = 0; cnt2[tid] = 0; }
  gpre[tid] = (tid < NBUCK) ? gcursor[tid] : 0;
  __syncthreads();
  // inclusive scan over 512 (bucket counts)
  for (int off = 1; off < 512; off <<= 1) {
    int t = (tid >= off) ? gpre[tid - off] : 0;
    __syncthreads();
    gpre[tid] += t;
    __syncthreads();
  }
  const int cnt = gcursor[b];
  const int gbase = (b == 0) ? 0 : gpre[b - 1];
  const unsigned* bp = pairs + (size_t)b * BCAP;
  if (b == 0 && tid == 0) row_ptr[N] = Etot;

  for (int i = tid; i < cnt; i += 512) {
    unsigned p = bp[i];
    atomicAdd(&hist[p >> 16], 1);
  }
  __syncthreads();
  if (tid < 128) offs[tid] = hist[tid];
  __syncthreads();
  for (int off = 1; off < 128; off <<= 1) {
    int t = 0;
    if (tid < 128 && tid >= off) t = offs[tid - off];
    __syncthreads();
    if (tid < 128) offs[tid] += t;
    __syncthreads();
  }
  if (tid < 128) {
    int node = b * 128 + tid;
    if (node < N) row_ptr[node] = gbase + offs[tid] - hist[tid];
  }
  __syncthreads();
  for (int i = tid; i < cnt; i += 512) {
    unsigned p = bp[i];
    int lo = (int)(p >> 16);
    int src = (int)(p & 0xffffu);
    int rank = atomicAdd(&cnt2[lo], 1);
    int pos = gbase + offs[lo] - hist[lo] + rank;
    float4 a = as1[src], dd = ad1[b * 128 + lo];
    float s0 = a.x + dd.x, s1 = a.y + dd.y, s2 = a.z + dd.z, s3 = a.w + dd.w;
    float w0 = exp2f(fmaxf(s0, NEG_SLOPE * s0));
    float w1 = exp2f(fmaxf(s1, NEG_SLOPE * s1));
    float w2 = exp2f(fmaxf(s2, NEG_SLOPE * s2));
    float w3 = exp2f(fmaxf(s3, NEG_SLOPE * s3));
    unsigned w01 = (unsigned)f2bf(w0) | ((unsigned)f2bf(w1) << 16);
    unsigned w23 = (unsigned)f2bf(w2) | ((unsigned)f2bf(w3) << 16);
    src16[pos] = (unsigned short)src;
    w4[pos] = (ull)w01 | ((ull)w23 << 32);
  }
}

// ---------------- fused: layer-1 aggregate + GEMM2 + alpha2 dots ----------------
// edge loop software-pipelined: next 8 edges' metadata loads overlap current gathers.
__global__ __launch_bounds__(256) void agg1_gemm2(const unsigned char* __restrict__ H8,
                                                  const unsigned short* __restrict__ src16,
                                                  const ull* __restrict__ w4,
                                                  const int* __restrict__ row_ptr,
                                                  const float* __restrict__ b1,
                                                  const unsigned short* __restrict__ W2b,
                                                  const float* __restrict__ att_s2,
                                                  const float* __restrict__ att_d2,
                                                  unsigned char* __restrict__ H2,
                                                  float* __restrict__ as2,
                                                  float* __restrict__ ad2, int n) {
  __shared__ unsigned char lds_h[16 * 512];   // 16 rows x 256 bf16, swizzled
  __shared__ float pA[4][16], pD[4][16];
  const int tid = threadIdx.x;
  const int l = tid & 63, w = tid >> 6;
  const int dbase = blockIdx.x * 16;
  const int hh = l >> 4;
  const int shamt = (hh & 1) ? 0 : 16;
  const bool lowpair = hh < 2;
  const float4 bb = *(const float4*)(b1 + l * 4);

  // preload all row bounds for this wave's 4 dsts (5 scalar loads, issued together)
  const int dw = dbase + w * 4;
  int bnd[5];
#pragma unroll
  for (int j = 0; j < 5; j++) bnd[j] = row_ptr[min(dw + j, n)];

#define WSEL(wv) __uint_as_float((((lowpair) ? (unsigned)(wv) : (unsigned)((wv) >> 32)) << shamt) & 0xffff0000u)
#define ACCUM(wgt, u8)                                                     \
  {                                                                        \
    f32x2 lo_ = __builtin_amdgcn_cvt_pk_f32_fp8((int)(u8), false);         \
    f32x2 hi_ = __builtin_amdgcn_cvt_pk_f32_fp8((int)(u8), true);          \
    accA += lo_ * (wgt); accB += hi_ * (wgt);                              \
    denom += (wgt);                                                        \
  }
  for (int i = 0; i < 4; i++) {
    int dloc = w * 4 + i;
    int d = dbase + dloc;
    bool active = d < n;
    f32x2 accA = {0.f, 0.f}, accB = {0.f, 0.f};
    float denom = 0.f;
    if (active) {
      int e0 = __builtin_amdgcn_readfirstlane(bnd[i]);
      int e1 = __builtin_amdgcn_readfirstlane(bnd[i + 1]);
      int e = e0;
      unsigned sc[8]; ull wc[8];
      if (e + 8 <= e1) {
#pragma unroll
        for (int j = 0; j < 8; j++) { sc[j] = src16[e + j]; wc[j] = w4[e + j]; }
      }
      for (; e + 16 <= e1; e += 8) {
        unsigned sn[8]; ull wn[8];
#pragma unroll
        for (int j = 0; j < 8; j++) { sn[j] = src16[e + 8 + j]; wn[j] = w4[e + 8 + j]; }
#pragma unroll
        for (int j = 0; j < 8; j++) {
          unsigned u = *(const unsigned*)(H8 + (size_t)sc[j] * C1 + l * 4);
          float wq = WSEL(wc[j]);
          ACCUM(wq, u)
        }
#pragma unroll
        for (int j = 0; j < 8; j++) { sc[j] = sn[j]; wc[j] = wn[j]; }
      }
      if (e + 8 <= e1) {
#pragma unroll
        for (int j = 0; j < 8; j++) {
          unsigned u = *(const unsigned*)(H8 + (size_t)sc[j] * C1 + l * 4);
          float wq = WSEL(wc[j]);
          ACCUM(wq, u)
        }
        e += 8;
      }
      for (; e < e1; e++) {
        unsigned s0 = src16[e];
        ull wv = w4[e];
        unsigned u = *(const unsigned*)(H8 + (size_t)s0 * C1 + l * 4);
        float wq = WSEL(wv);
        ACCUM(wq, u)
      }
    }
    float inv = 1.f / (denom + 1e-16f);
    float4 o;
    o.x = accA[0] * inv + bb.x; o.y = accA[1] * inv + bb.y;
    o.z = accB[0] * inv + bb.z; o.w = accB[1] * inv + bb.w;
    o.x = o.x > 0.f ? o.x : (__expf(o.x) - 1.f);
    o.y = o.y > 0.f ? o.y : (__expf(o.y) - 1.f);
    o.z = o.z > 0.f ? o.z : (__expf(o.z) - 1.f);
    o.w = o.w > 0.f ? o.w : (__expf(o.w) - 1.f);
    if (!active) { o.x = 0.f; o.y = 0.f; o.z = 0.f; o.w = 0.f; }
    uint2 pk;
    pk.x = (unsigned int)f2bf(o.x) | ((unsigned int)f2bf(o.y) << 16);
    pk.y = (unsigned int)f2bf(o.z) | ((unsigned int)f2bf(o.w) << 16);
    unsigned byte = (unsigned)(l * 8) ^ ((unsigned)(dloc & 7) << 4);
    *(uint2*)(lds_h + dloc * 512 + byte) = pk;
  }
#undef ACCUM
#undef WSEL
  __syncthreads();

  const int li2 = l & 15, g2 = l >> 4;
  f32x4 acc2;
  acc2[0] = 0.f; acc2[1] = 0.f; acc2[2] = 0.f; acc2[3] = 0.f;
#pragma unroll
  for (int ks = 0; ks < 8; ks++) {
    unsigned byte = (unsigned)((ks * 32 + g2 * 8) * 2) ^ ((unsigned)(li2 & 7) << 4);
    bf16x8 a = *(const bf16x8*)(lds_h + li2 * 512 + byte);
    bf16x8 b = *(const bf16x8*)(W2b + ((size_t)(ks * 4 + w) * 64 + l) * 8);
    acc2 = __builtin_amdgcn_mfma_f32_16x16x32_bf16(a, b, acc2, 0, 0, 0);
  }

  float ws = att_s2[w * 16 + li2], wd = att_d2[w * 16 + li2];
  float asum[4], dsum[4];
#pragma unroll
  for (int r = 0; r < 4; r++) { asum[r] = acc2[r] * ws; dsum[r] = acc2[r] * wd; }
#pragma unroll
  for (int r = 0; r < 4; r++) {
#pragma unroll
    for (int m = 1; m < 16; m <<= 1) {
      asum[r] += __shfl_xor(asum[r], m);
      dsum[r] += __shfl_xor(dsum[r], m);
    }
  }
#pragma unroll
  for (int r = 0; r < 4; r++) {
    int row = g2 * 4 + r;
    int d2 = dbase + row;
    if (d2 < n) H2[(size_t)d2 * HID + w * 16 + li2] = f2fp8(acc2[r]);
    if (li2 == 0) { pA[w][row] = asum[r]; pD[w][row] = dsum[r]; }
  }
  __syncthreads();
  if (tid < 16) {
    int d2 = dbase + tid;
    if (d2 < n) as2[d2] = (pA[0][tid] + pA[1][tid] + pA[2][tid] + pA[3][tid]) * LOG2E;
  } else if (tid < 32) {
    int row = tid - 16;
    int d2 = dbase + row;
    if (d2 < n) ad2[d2] = (pD[0][row] + pD[1][row] + pD[2][row] + pD[3][row]) * LOG2E;
  }
}

// ---------------- layer-2 aggregate (fp8 gather, src16 stream) + mean pool ------
__global__ __launch_bounds__(256) void agg2_pool(const unsigned char* __restrict__ H2,
                                                 const float* __restrict__ as_,
                                                 const float* __restrict__ ad_,
                                                 const int* __restrict__ row_ptr,
                                                 const unsigned short* __restrict__ src16,
                                                 const float* __restrict__ b2,
                                                 float* __restrict__ poolrep, int n) {
  __shared__ float lds[4][64];
  int wid = threadIdx.x >> 6;
  int d = blockIdx.x * 4 + wid;
  int l = threadIdx.x & 63, q = l >> 4, li = l & 15;
  float ad = ad_[d];
  int e0 = __builtin_amdgcn_readfirstlane(row_ptr[d]);
  int e1 = __builtin_amdgcn_readfirstlane(row_ptr[d + 1]);
  f32x2 accA = {0.f, 0.f}, accB = {0.f, 0.f};
  float denom = 0.f;
  int e = e0 + q;
  for (; e + 4 < e1; e += 8) {
    int sa = (int)src16[e];
    int sb = (int)src16[e + 4];
    float sca = as_[sa] + ad, scb = as_[sb] + ad;
    float wa = exp2f(fmaxf(sca, NEG_SLOPE * sca));
    float wb = exp2f(fmaxf(scb, NEG_SLOPE * scb));
    unsigned ua = *(const unsigned*)(H2 + (size_t)sa * HID + li * 4);
    unsigned ub = *(const unsigned*)(H2 + (size_t)sb * HID + li * 4);
    f32x2 loa = __builtin_amdgcn_cvt_pk_f32_fp8((int)ua, false);
    f32x2 hia = __builtin_amdgcn_cvt_pk_f32_fp8((int)ua, true);
    f32x2 lob = __builtin_amdgcn_cvt_pk_f32_fp8((int)ub, false);
    f32x2 hib = __builtin_amdgcn_cvt_pk_f32_fp8((int)ub, true);
    accA += loa * wa; accB += hia * wa;
    accA += lob * wb; accB += hib * wb;
    denom += wa + wb;
  }
  for (; e < e1; e += 4) {
    int s = (int)src16[e];
    float sc = as_[s] + ad;
    float w = exp2f(fmaxf(sc, NEG_SLOPE * sc));
    denom += w;
    unsigned u = *(const unsigned*)(H2 + (size_t)s * HID + li * 4);
    f32x2 lo_ = __builtin_amdgcn_cvt_pk_f32_fp8((int)u, false);
    f32x2 hi_ = __builtin_amdgcn_cvt_pk_f32_fp8((int)u, true);
    accA += lo_ * w; accB += hi_ * w;
  }
#pragma unroll
  for (int m = 16; m <= 32; m <<= 1) {
    accA[0] += __shfl_xor(accA[0], m); accA[1] += __shfl_xor(accA[1], m);
    accB[0] += __shfl_xor(accB[0], m); accB[1] += __shfl_xor(accB[1], m);
    denom += __shfl_xor(denom, m);
  }
  if (q == 0) {
    float inv = 1.f / (denom + 1e-16f);
    float o[4] = {accA[0] * inv + b2[li * 4], accA[1] * inv + b2[li * 4 + 1],
                  accB[0] * inv + b2[li * 4 + 2], accB[1] * inv + b2[li * 4 + 3]};
#pragma unroll
    for (int j = 0; j < 4; j++) {
      float v = o[j];
      lds[wid][li * 4 + j] = v > 0.f ? v : (__expf(v) - 1.f);
    }
  }
  __syncthreads();
  if (threadIdx.x < 64) {
    int c = threadIdx.x;
    float v = lds[0][c] + lds[1][c] + lds[2][c] + lds[3][c];
    atomicAdd(&poolrep[(blockIdx.x & 63) * 64 + c], v);
  }
}

__global__ __launch_bounds__(64) void head_kernel(const float* __restrict__ poolrep,
                                                  const float* __restrict__ Wc,
                                                  const float* __restrict__ bc,
                                                  float* __restrict__ out, float inv_n) {
  int l = threadIdx.x;
  float p = 0.f;
  for (int k = 0; k < 64; k++) p += poolrep[k * 64 + l];
  p *= inv_n;
  float o0 = wave_reduce_sum(p * Wc[l * 2 + 0]);
  float o1 = wave_reduce_sum(p * Wc[l * 2 + 1]);
  if (l == 0) { out[0] = o0 + bc[0]; out[1] = o1 + bc[1]; }
}

// ---------------- host ----------------
static inline size_t align256(size_t x) { return (x + 255) & ~(size_t)255; }

extern "C" void kernel_launch(void* const* d_in, const int* in_sizes, int n_in,
                              void* d_out, int out_size, void* d_ws, size_t ws_size,
                              hipStream_t stream) {
  const float* x        = (const float*)d_in[0];
  const int*   ei       = (const int*)d_in[1];
  const float* W1       = (const float*)d_in[2];
  const float* att_src1 = (const float*)d_in[3];
  const float* att_dst1 = (const float*)d_in[4];
  const float* b1       = (const float*)d_in[5];
  const float* W2       = (const float*)d_in[6];
  const float* att_src2 = (const float*)d_in[7];
  const float* att_dst2 = (const float*)d_in[8];
  const float* b2       = (const float*)d_in[9];
  const float* Wc       = (const float*)d_in[10];
  const float* bc       = (const float*)d_in[11];
  float* out = (float*)d_out;

  const int N = in_sizes[0] / F_IN;          // 50000
  const int E = in_sizes[1] / 2;             // 1,600,000
  const int Etot = E + N;                    // + self loops
  const int* ei_src = ei;
  const int* ei_dst = ei + E;

  // workspace layout (~46 MB)
  char* w = (char*)d_ws;
  size_t off = 0;
  unsigned char* h1b8 = (unsigned char*)(w + off); off += align256((size_t)N * C1);   // 12.8MB fp8
  unsigned char* h2b8 = (unsigned char*)(w + off); off += align256((size_t)N * HID);  // 3.2MB fp8
  float* as1   = (float*)(w + off); off += align256((size_t)N * HEADS * 4);
  float* ad1   = (float*)(w + off); off += align256((size_t)N * HEADS * 4);
  float* as2   = (float*)(w + off); off += align256((size_t)N * 4);
  float* ad2   = (float*)(w + off); off += align256((size_t)N * 4);
  int* row_ptr = (int*)(w + off);   off += align256((size_t)(N + 1) * 4);
  int* gcursor = (int*)(w + off);   off += align256(512 * 4);
  float* poolrep = (float*)(w + off); off += align256(64 * 64 * 4);
  unsigned short* W1b = (unsigned short*)(w + off); off += align256(32768 * 2);
  unsigned short* W2b = (unsigned short*)(w + off); off += align256(16384 * 2);
  unsigned* pairs = (unsigned*)(w + off); off += align256((size_t)NBUCK * BCAP * 4);  // 8MB
  unsigned short* src16 = (unsigned short*)(w + off); off += align256((size_t)Etot * 2);
  ull* w4      = (ull*)(w + off);   off += align256((size_t)Etot * 8);

  int nb4 = (N + 3) / 4;
  int rowblocks = (N + 63) / 64;             // 782
  int pblocks = (Etot + 2047) / 2048;        // 806
  int fblocks = (N + 15) / 16;               // 3125

  setup_kernel<<<104, 256, 0, stream>>>(W1, W2, W1b, W2b, gcursor, poolrep);
  gemm1_partition<<<rowblocks + pblocks, 256, 0, stream>>>(
      x, W1b, h1b8, as1, ad1, att_src1, att_dst1, N, rowblocks,
      ei_src, ei_dst, gcursor, pairs, E, Etot);
  bucket_csr<<<NBUCK, 512, 0, stream>>>(pairs, gcursor,
                                        (const float4*)as1, (const float4*)ad1,
                                        src16, w4, row_ptr, N, Etot);
  agg1_gemm2<<<fblocks, 256, 0, stream>>>(h1b8, src16, w4, row_ptr, b1, W2b,
                                          att_src2, att_dst2, h2b8, as2, ad2, N);
  agg2_pool<<<nb4, 256, 0, stream>>>(h2b8, as2, ad2, row_ptr, src16, b2, poolrep, N);
  head_kernel<<<1, 64, 0, stream>>>(poolrep, Wc, bc, out, 1.0f / (float)N);
}

// Round 18
// 180.784 us; speedup vs baseline: 1.0603x; 1.0603x over previous
//
#include <hip/hip_runtime.h>
#include <cstdint>
#include <cstddef>

#define NEG_SLOPE 0.2f
#define F_IN 128
#define C1 256      // HEADS*HID layer-1 width
#define HID 64
#define HEADS 4
#define LOG2E 1.4426950408889634f
#define NBUCK 392   // ceil(50000/128)
#define BCAP 5120   // per-bucket capacity (mean 4224, sigma ~65)

typedef __attribute__((ext_vector_type(8))) short bf16x8;
typedef __attribute__((ext_vector_type(4))) float f32x4;
typedef __attribute__((ext_vector_type(2))) float f32x2;
typedef unsigned long long ull;

__device__ __forceinline__ float wave_reduce_sum(float v) {
#pragma unroll
  for (int off = 32; off > 0; off >>= 1) v += __shfl_down(v, off);
  return v;
}

__device__ __forceinline__ unsigned short f2bf(float f) {
  union { float f; unsigned int u; } v; v.f = f;
  unsigned int u = v.u;
  unsigned int r = (u + 0x7fffu + ((u >> 16) & 1u)) >> 16;  // RNE
  return (unsigned short)r;
}

__device__ __forceinline__ unsigned char f2fp8(float f) {
  int p = __builtin_amdgcn_cvt_pk_fp8_f32(f, f, 0, false);  // OCP e4m3fn
  return (unsigned char)(p & 0xff);
}

// ---------------- setup: zero gcursor/poolrep + weight pre-pack (merged) --------
__global__ __launch_bounds__(256) void setup_kernel(const float* __restrict__ W1,
                                                    const float* __restrict__ W2,
                                                    unsigned short* __restrict__ W1b,
                                                    unsigned short* __restrict__ W2b,
                                                    int* __restrict__ gcursor,
                                                    float* __restrict__ poolrep) {
  const int TOT = 512 + 4096 + 32768 + 16384;
  for (int idx = threadIdx.x + blockIdx.x * 256; idx < TOT; idx += 256 * gridDim.x) {
    if (idx < 512) {
      gcursor[idx] = 0;
    } else if (idx < 512 + 4096) {
      poolrep[idx - 512] = 0.f;
    } else if (idx < 512 + 4096 + 32768) {
      int o = idx - (512 + 4096);
      int head = o >> 13, ks = (o >> 11) & 3, nt = (o >> 9) & 3;
      int lane = (o >> 3) & 63, j = o & 7;
      int k = ks * 32 + (lane >> 4) * 8 + j;
      int c = head * 64 + nt * 16 + (lane & 15);
      W1b[o] = f2bf(W1[k * 256 + c]);
    } else {
      int o = idx - (512 + 4096 + 32768);
      int ks = o >> 11, nt = (o >> 9) & 3, lane = (o >> 3) & 63, j = o & 7;
      int k = ks * 32 + (lane >> 4) * 8 + j;
      int c = nt * 16 + (lane & 15);
      W2b[o] = f2bf(W2[k * 64 + c]);
    }
  }
}

// ---------------- fat kernel: GEMM1 (blocks < rowblocks) + edge partition ------
__global__ __launch_bounds__(256) void gemm1_partition(const float* __restrict__ Af,
                                                       const unsigned short* __restrict__ Wb,
                                                       unsigned char* __restrict__ H8,
                                                       float* __restrict__ as_out,
                                                       float* __restrict__ ad_out,
                                                       const float* __restrict__ att_s,
                                                       const float* __restrict__ att_d,
                                                       int M, int rowblocks,
                                                       const int* __restrict__ esrc,
                                                       const int* __restrict__ edst,
                                                       int* __restrict__ gcursor,
                                                       unsigned* __restrict__ pairs,
                                                       int E, int Etot) {
  __shared__ int hist[512];
  __shared__ int base[512];
  if (blockIdx.x < rowblocks) {
    // ---- GEMM1: fp32 A -> bf16 MFMA, fp8 h-store, all heads ----
    constexpr int KSTEPS = 4, NH = HEADS, K = 128, N = 256;
    const int lane = threadIdx.x & 63, wid = threadIdx.x >> 6;
    const int rowbase = blockIdx.x * 64 + wid * 16;
    const int g = lane >> 4, li = lane & 15;
    int r_a = rowbase + li;
    if (r_a > M - 1) r_a = M - 1;

    f32x4 acc[NH][4];
#pragma unroll
    for (int h = 0; h < NH; h++)
#pragma unroll
      for (int nt = 0; nt < 4; nt++) {
        acc[h][nt][0] = 0.f; acc[h][nt][1] = 0.f; acc[h][nt][2] = 0.f; acc[h][nt][3] = 0.f;
      }

#pragma unroll
    for (int ks = 0; ks < KSTEPS; ks++) {
      bf16x8 a;
      const float* p = Af + (size_t)r_a * K + ks * 32 + g * 8;
      float4 v0 = *(const float4*)p, v1 = *(const float4*)(p + 4);
      a[0] = (short)f2bf(v0.x); a[1] = (short)f2bf(v0.y);
      a[2] = (short)f2bf(v0.z); a[3] = (short)f2bf(v0.w);
      a[4] = (short)f2bf(v1.x); a[5] = (short)f2bf(v1.y);
      a[6] = (short)f2bf(v1.z); a[7] = (short)f2bf(v1.w);
#pragma unroll
      for (int h = 0; h < NH; h++)
#pragma unroll
        for (int nt = 0; nt < 4; nt++) {
          bf16x8 b = *(const bf16x8*)(Wb + ((size_t)((h * KSTEPS + ks) * 4 + nt) * 64 + lane) * 8);
          acc[h][nt] = __builtin_amdgcn_mfma_f32_16x16x32_bf16(a, b, acc[h][nt], 0, 0, 0);
        }
    }

#pragma unroll
    for (int h = 0; h < NH; h++) {
      float asum[4] = {0.f, 0.f, 0.f, 0.f}, dsum[4] = {0.f, 0.f, 0.f, 0.f};
#pragma unroll
      for (int nt = 0; nt < 4; nt++) {
        float ws = att_s[h * 64 + nt * 16 + li];
        float wd = att_d[h * 64 + nt * 16 + li];
#pragma unroll
        for (int r = 0; r < 4; r++) { asum[r] += acc[h][nt][r] * ws; dsum[r] += acc[h][nt][r] * wd; }
      }
#pragma unroll
      for (int r = 0; r < 4; r++) {
#pragma unroll
        for (int m = 1; m < 16; m <<= 1) {
          asum[r] += __shfl_xor(asum[r], m);
          dsum[r] += __shfl_xor(dsum[r], m);
        }
      }
#pragma unroll
      for (int r = 0; r < 4; r++) {
        int gr = rowbase + g * 4 + r;
        if (gr < M) {
#pragma unroll
          for (int nt = 0; nt < 4; nt++)
            H8[(size_t)gr * N + h * 64 + nt * 16 + li] = f2fp8(acc[h][nt][r]);
          if (li == 0) {
            as_out[(size_t)gr * NH + h] = asum[r] * LOG2E;
            ad_out[(size_t)gr * NH + h] = dsum[r] * LOG2E;
          }
        }
      }
    }
  } else {
    // ---- partition: packed 4B pairs into 392 coarse buckets (dst>>7) ----
    const int tid = threadIdx.x;
    const int e0 = (blockIdx.x - rowblocks) * 2048;
    hist[tid] = 0; hist[tid + 256] = 0;
    __syncthreads();
    int d8[8], rk8[8], bk8[8];
#pragma unroll
    for (int j = 0; j < 8; j++) {
      int e = e0 + tid * 8 + j;
      d8[j] = -1;
      if (e < Etot) {
        int d = (e < E) ? edst[e] : (e - E);
        d8[j] = d;
        bk8[j] = d >> 7;
        rk8[j] = atomicAdd(&hist[bk8[j]], 1);
      }
    }
    __syncthreads();
    if (hist[tid] > 0) base[tid] = atomicAdd(&gcursor[tid], hist[tid]);
    if (hist[tid + 256] > 0) base[tid + 256] = atomicAdd(&gcursor[tid + 256], hist[tid + 256]);
    __syncthreads();
#pragma unroll
    for (int j = 0; j < 8; j++) {
      int e = e0 + tid * 8 + j;
      if (e < Etot) {
        int s = (e < E) ? esrc[e] : (e - E);
        pairs[(size_t)bk8[j] * BCAP + base[bk8[j]] + rk8[j]] =
            (unsigned)s | ((unsigned)(d8[j] & 127) << 16);
      }
    }
  }
}

// per-bucket CSR (128 dsts) + fused edge weights; computes its own bucket prefix.
__global__ __launch_bounds__(512) void bucket_csr(const unsigned* __restrict__ pairs,
                                                  const int* __restrict__ gcursor,
                                                  const float4* __restrict__ as1,
                                                  const float4* __restrict__ ad1,
                                                  unsigned short* __restrict__ src16,
                                                  ull* __restrict__ w4,
                                                  int* __restrict__ row_ptr,
                                                  int N, int Etot) {
  __shared__ int hist[128], offs[128], cnt2[128], gpre[512];
  const int b = blockIdx.x;
  const int tid = threadIdx.x;
  if (tid < 128) { hist[tid] = 0; cnt2[tid] = 0; }
  gpre[tid] = (tid < NBUCK) ? gcursor[tid] : 0;
  __syncthreads();
  // inclusive scan over 512 (bucket counts)
  for (int off = 1; off < 512; off <<= 1) {
    int t = (tid >= off) ? gpre[tid - off] : 0;
    __syncthreads();
    gpre[tid] += t;
    __syncthreads();
  }
  const int cnt = gcursor[b];
  const int gbase = (b == 0) ? 0 : gpre[b - 1];
  const unsigned* bp = pairs + (size_t)b * BCAP;
  if (b == 0 && tid == 0) row_ptr[N] = Etot;

  for (int i = tid; i < cnt; i += 512) {
    unsigned p = bp[i];
    atomicAdd(&hist[p >> 16], 1);
  }
  __syncthreads();
  if (tid < 128) offs[tid] = hist[tid];
  __syncthreads();
  for (int off = 1; off < 128; off <<= 1) {
    int t = 0;
    if (tid < 128 && tid >= off) t = offs[tid - off];
    __syncthreads();
    if (tid < 128) offs[tid] += t;
    __syncthreads();
  }
  if (tid < 128) {
    int node = b * 128 + tid;
    if (node < N) row_ptr[node] = gbase + offs[tid] - hist[tid];
  }
  __syncthreads();
  for (int i = tid; i < cnt; i += 512) {
    unsigned p = bp[i];
    int lo = (int)(p >> 16);
    int src = (int)(p & 0xffffu);
    int rank = atomicAdd(&cnt2[lo], 1);
    int pos = gbase + offs[lo] - hist[lo] + rank;
    float4 a = as1[src], dd = ad1[b * 128 + lo];
    float s0 = a.x + dd.x, s1 = a.y + dd.y, s2 = a.z + dd.z, s3 = a.w + dd.w;
    float w0 = exp2f(fmaxf(s0, NEG_SLOPE * s0));
    float w1 = exp2f(fmaxf(s1, NEG_SLOPE * s1));
    float w2 = exp2f(fmaxf(s2, NEG_SLOPE * s2));
    float w3 = exp2f(fmaxf(s3, NEG_SLOPE * s3));
    unsigned w01 = (unsigned)f2bf(w0) | ((unsigned)f2bf(w1) << 16);
    unsigned w23 = (unsigned)f2bf(w2) | ((unsigned)f2bf(w3) << 16);
    src16[pos] = (unsigned short)src;
    w4[pos] = (ull)w01 | ((ull)w23 << 32);
  }
}

// ---------------- fused: layer-1 aggregate + GEMM2 + alpha2 dots ----------------
__global__ __launch_bounds__(256) void agg1_gemm2(const unsigned char* __restrict__ H8,
                                                  const unsigned short* __restrict__ src16,
                                                  const ull* __restrict__ w4,
                                                  const int* __restrict__ row_ptr,
                                                  const float* __restrict__ b1,
                                                  const unsigned short* __restrict__ W2b,
                                                  const float* __restrict__ att_s2,
                                                  const float* __restrict__ att_d2,
                                                  unsigned char* __restrict__ H2,
                                                  float* __restrict__ as2,
                                                  float* __restrict__ ad2, int n) {
  __shared__ unsigned char lds_h[16 * 512];   // 16 rows x 256 bf16, swizzled
  __shared__ float pA[4][16], pD[4][16];
  const int tid = threadIdx.x;
  const int l = tid & 63, w = tid >> 6;
  const int dbase = blockIdx.x * 16;
  const int hh = l >> 4;
  const int shamt = (hh & 1) ? 0 : 16;
  const bool lowpair = hh < 2;
  const float4 bb = *(const float4*)(b1 + l * 4);

  // preload all row bounds for this wave's 4 dsts (5 scalar loads, issued together)
  const int dw = dbase + w * 4;
  int bnd[5];
#pragma unroll
  for (int j = 0; j < 5; j++) bnd[j] = row_ptr[min(dw + j, n)];

#define WSEL(wv) __uint_as_float((((lowpair) ? (unsigned)(wv) : (unsigned)((wv) >> 32)) << shamt) & 0xffff0000u)
#define ACCUM(wgt, u8)                                                     \
  {                                                                        \
    f32x2 lo_ = __builtin_amdgcn_cvt_pk_f32_fp8((int)(u8), false);         \
    f32x2 hi_ = __builtin_amdgcn_cvt_pk_f32_fp8((int)(u8), true);          \
    accA += lo_ * (wgt); accB += hi_ * (wgt);                              \
    denom += (wgt);                                                        \
  }
  for (int i = 0; i < 4; i++) {
    int dloc = w * 4 + i;
    int d = dbase + dloc;
    bool active = d < n;
    f32x2 accA = {0.f, 0.f}, accB = {0.f, 0.f};
    float denom = 0.f;
    if (active) {
      int e0 = __builtin_amdgcn_readfirstlane(bnd[i]);
      int e1 = __builtin_amdgcn_readfirstlane(bnd[i + 1]);
      int e = e0;
      for (; e + 7 < e1; e += 8) {
        unsigned s0 = src16[e],     s1 = src16[e + 1];
        unsigned s2 = src16[e + 2], s3 = src16[e + 3];
        unsigned s4 = src16[e + 4], s5 = src16[e + 5];
        unsigned s6 = src16[e + 6], s7 = src16[e + 7];
        ull wv0 = w4[e],     wv1 = w4[e + 1], wv2 = w4[e + 2], wv3 = w4[e + 3];
        ull wv4 = w4[e + 4], wv5 = w4[e + 5], wv6 = w4[e + 6], wv7 = w4[e + 7];
        unsigned u0 = *(const unsigned*)(H8 + (size_t)s0 * C1 + l * 4);
        unsigned u1 = *(const unsigned*)(H8 + (size_t)s1 * C1 + l * 4);
        unsigned u2 = *(const unsigned*)(H8 + (size_t)s2 * C1 + l * 4);
        unsigned u3 = *(const unsigned*)(H8 + (size_t)s3 * C1 + l * 4);
        unsigned u4 = *(const unsigned*)(H8 + (size_t)s4 * C1 + l * 4);
        unsigned u5 = *(const unsigned*)(H8 + (size_t)s5 * C1 + l * 4);
        unsigned u6 = *(const unsigned*)(H8 + (size_t)s6 * C1 + l * 4);
        unsigned u7 = *(const unsigned*)(H8 + (size_t)s7 * C1 + l * 4);
        float w0 = WSEL(wv0), w1 = WSEL(wv1), w2 = WSEL(wv2), w3 = WSEL(wv3);
        float w4_ = WSEL(wv4), w5 = WSEL(wv5), w6 = WSEL(wv6), w7 = WSEL(wv7);
        ACCUM(w0, u0) ACCUM(w1, u1) ACCUM(w2, u2) ACCUM(w3, u3)
        ACCUM(w4_, u4) ACCUM(w5, u5) ACCUM(w6, u6) ACCUM(w7, u7)
      }
      for (; e < e1; e++) {
        unsigned s0 = src16[e];
        ull wv = w4[e];
        unsigned u = *(const unsigned*)(H8 + (size_t)s0 * C1 + l * 4);
        float wq = WSEL(wv);
        ACCUM(wq, u)
      }
    }
    float inv = 1.f / (denom + 1e-16f);
    float4 o;
    o.x = accA[0] * inv + bb.x; o.y = accA[1] * inv + bb.y;
    o.z = accB[0] * inv + bb.z; o.w = accB[1] * inv + bb.w;
    o.x = o.x > 0.f ? o.x : (__expf(o.x) - 1.f);
    o.y = o.y > 0.f ? o.y : (__expf(o.y) - 1.f);
    o.z = o.z > 0.f ? o.z : (__expf(o.z) - 1.f);
    o.w = o.w > 0.f ? o.w : (__expf(o.w) - 1.f);
    if (!active) { o.x = 0.f; o.y = 0.f; o.z = 0.f; o.w = 0.f; }
    uint2 pk;
    pk.x = (unsigned int)f2bf(o.x) | ((unsigned int)f2bf(o.y) << 16);
    pk.y = (unsigned int)f2bf(o.z) | ((unsigned int)f2bf(o.w) << 16);
    unsigned byte = (unsigned)(l * 8) ^ ((unsigned)(dloc & 7) << 4);
    *(uint2*)(lds_h + dloc * 512 + byte) = pk;
  }
#undef ACCUM
#undef WSEL
  __syncthreads();

  const int li2 = l & 15, g2 = l >> 4;
  f32x4 acc2;
  acc2[0] = 0.f; acc2[1] = 0.f; acc2[2] = 0.f; acc2[3] = 0.f;
#pragma unroll
  for (int ks = 0; ks < 8; ks++) {
    unsigned byte = (unsigned)((ks * 32 + g2 * 8) * 2) ^ ((unsigned)(li2 & 7) << 4);
    bf16x8 a = *(const bf16x8*)(lds_h + li2 * 512 + byte);
    bf16x8 b = *(const bf16x8*)(W2b + ((size_t)(ks * 4 + w) * 64 + l) * 8);
    acc2 = __builtin_amdgcn_mfma_f32_16x16x32_bf16(a, b, acc2, 0, 0, 0);
  }

  float ws = att_s2[w * 16 + li2], wd = att_d2[w * 16 + li2];
  float asum[4], dsum[4];
#pragma unroll
  for (int r = 0; r < 4; r++) { asum[r] = acc2[r] * ws; dsum[r] = acc2[r] * wd; }
#pragma unroll
  for (int r = 0; r < 4; r++) {
#pragma unroll
    for (int m = 1; m < 16; m <<= 1) {
      asum[r] += __shfl_xor(asum[r], m);
      dsum[r] += __shfl_xor(dsum[r], m);
    }
  }
#pragma unroll
  for (int r = 0; r < 4; r++) {
    int row = g2 * 4 + r;
    int d2 = dbase + row;
    if (d2 < n) H2[(size_t)d2 * HID + w * 16 + li2] = f2fp8(acc2[r]);
    if (li2 == 0) { pA[w][row] = asum[r]; pD[w][row] = dsum[r]; }
  }
  __syncthreads();
  if (tid < 16) {
    int d2 = dbase + tid;
    if (d2 < n) as2[d2] = (pA[0][tid] + pA[1][tid] + pA[2][tid] + pA[3][tid]) * LOG2E;
  } else if (tid < 32) {
    int row = tid - 16;
    int d2 = dbase + row;
    if (d2 < n) ad2[d2] = (pD[0][row] + pD[1][row] + pD[2][row] + pD[3][row]) * LOG2E;
  }
}

// ---------------- layer-2 aggregate (fp8 gather, src16 stream) + mean pool ------
__global__ __launch_bounds__(256) void agg2_pool(const unsigned char* __restrict__ H2,
                                                 const float* __restrict__ as_,
                                                 const float* __restrict__ ad_,
                                                 const int* __restrict__ row_ptr,
                                                 const unsigned short* __restrict__ src16,
                                                 const float* __restrict__ b2,
                                                 float* __restrict__ poolrep, int n) {
  __shared__ float lds[4][64];
  int wid = threadIdx.x >> 6;
  int d = blockIdx.x * 4 + wid;
  int l = threadIdx.x & 63, q = l >> 4, li = l & 15;
  float ad = ad_[d];
  int e0 = __builtin_amdgcn_readfirstlane(row_ptr[d]);
  int e1 = __builtin_amdgcn_readfirstlane(row_ptr[d + 1]);
  f32x2 accA = {0.f, 0.f}, accB = {0.f, 0.f};
  float denom = 0.f;
  int e = e0 + q;
  for (; e + 4 < e1; e += 8) {
    int sa = (int)src16[e];
    int sb = (int)src16[e + 4];
    float sca = as_[sa] + ad, scb = as_[sb] + ad;
    float wa = exp2f(fmaxf(sca, NEG_SLOPE * sca));
    float wb = exp2f(fmaxf(scb, NEG_SLOPE * scb));
    unsigned ua = *(const unsigned*)(H2 + (size_t)sa * HID + li * 4);
    unsigned ub = *(const unsigned*)(H2 + (size_t)sb * HID + li * 4);
    f32x2 loa = __builtin_amdgcn_cvt_pk_f32_fp8((int)ua, false);
    f32x2 hia = __builtin_amdgcn_cvt_pk_f32_fp8((int)ua, true);
    f32x2 lob = __builtin_amdgcn_cvt_pk_f32_fp8((int)ub, false);
    f32x2 hib = __builtin_amdgcn_cvt_pk_f32_fp8((int)ub, true);
    accA += loa * wa; accB += hia * wa;
    accA += lob * wb; accB += hib * wb;
    denom += wa + wb;
  }
  for (; e < e1; e += 4) {
    int s = (int)src16[e];
    float sc = as_[s] + ad;
    float w = exp2f(fmaxf(sc, NEG_SLOPE * sc));
    denom += w;
    unsigned u = *(const unsigned*)(H2 + (size_t)s * HID + li * 4);
    f32x2 lo_ = __builtin_amdgcn_cvt_pk_f32_fp8((int)u, false);
    f32x2 hi_ = __builtin_amdgcn_cvt_pk_f32_fp8((int)u, true);
    accA += lo_ * w; accB += hi_ * w;
  }
#pragma unroll
  for (int m = 16; m <= 32; m <<= 1) {
    accA[0] += __shfl_xor(accA[0], m); accA[1] += __shfl_xor(accA[1], m);
    accB[0] += __shfl_xor(accB[0], m); accB[1] += __shfl_xor(accB[1], m);
    denom += __shfl_xor(denom, m);
  }
  if (q == 0) {
    float inv = 1.f / (denom + 1e-16f);
    float o[4] = {accA[0] * inv + b2[li * 4], accA[1] * inv + b2[li * 4 + 1],
                  accB[0] * inv + b2[li * 4 + 2], accB[1] * inv + b2[li * 4 + 3]};
#pragma unroll
    for (int j = 0; j < 4; j++) {
      float v = o[j];
      lds[wid][li * 4 + j] = v > 0.f ? v : (__expf(v) - 1.f);
    }
  }
  __syncthreads();
  if (threadIdx.x < 64) {
    int c = threadIdx.x;
    float v = lds[0][c] + lds[1][c] + lds[2][c] + lds[3][c];
    atomicAdd(&poolrep[(blockIdx.x & 63) * 64 + c], v);
  }
}

__global__ __launch_bounds__(64) void head_kernel(const float* __restrict__ poolrep,
                                                  const float* __restrict__ Wc,
                                                  const float* __restrict__ bc,
                                                  float* __restrict__ out, float inv_n) {
  int l = threadIdx.x;
  float p = 0.f;
  for (int k = 0; k < 64; k++) p += poolrep[k * 64 + l];
  p *= inv_n;
  float o0 = wave_reduce_sum(p * Wc[l * 2 + 0]);
  float o1 = wave_reduce_sum(p * Wc[l * 2 + 1]);
  if (l == 0) { out[0] = o0 + bc[0]; out[1] = o1 + bc[1]; }
}

// ---------------- host ----------------
static inline size_t align256(size_t x) { return (x + 255) & ~(size_t)255; }

extern "C" void kernel_launch(void* const* d_in, const int* in_sizes, int n_in,
                              void* d_out, int out_size, void* d_ws, size_t ws_size,
                              hipStream_t stream) {
  const float* x        = (const float*)d_in[0];
  const int*   ei       = (const int*)d_in[1];
  const float* W1       = (const float*)d_in[2];
  const float* att_src1 = (const float*)d_in[3];
  const float* att_dst1 = (const float*)d_in[4];
  const float* b1       = (const float*)d_in[5];
  const float* W2       = (const float*)d_in[6];
  const float* att_src2 = (const float*)d_in[7];
  const float* att_dst2 = (const float*)d_in[8];
  const float* b2       = (const float*)d_in[9];
  const float* Wc       = (const float*)d_in[10];
  const float* bc       = (const float*)d_in[11];
  float* out = (float*)d_out;

  const int N = in_sizes[0] / F_IN;          // 50000
  const int E = in_sizes[1] / 2;             // 1,600,000
  const int Etot = E + N;                    // + self loops
  const int* ei_src = ei;
  const int* ei_dst = ei + E;

  // workspace layout (~46 MB)
  char* w = (char*)d_ws;
  size_t off = 0;
  unsigned char* h1b8 = (unsigned char*)(w + off); off += align256((size_t)N * C1);   // 12.8MB fp8
  unsigned char* h2b8 = (unsigned char*)(w + off); off += align256((size_t)N * HID);  // 3.2MB fp8
  float* as1   = (float*)(w + off); off += align256((size_t)N * HEADS * 4);
  float* ad1   = (float*)(w + off); off += align256((size_t)N * HEADS * 4);
  float* as2   = (float*)(w + off); off += align256((size_t)N * 4);
  float* ad2   = (float*)(w + off); off += align256((size_t)N * 4);
  int* row_ptr = (int*)(w + off);   off += align256((size_t)(N + 1) * 4);
  int* gcursor = (int*)(w + off);   off += align256(512 * 4);
  float* poolrep = (float*)(w + off); off += align256(64 * 64 * 4);
  unsigned short* W1b = (unsigned short*)(w + off); off += align256(32768 * 2);
  unsigned short* W2b = (unsigned short*)(w + off); off += align256(16384 * 2);
  unsigned* pairs = (unsigned*)(w + off); off += align256((size_t)NBUCK * BCAP * 4);  // 8MB
  unsigned short* src16 = (unsigned short*)(w + off); off += align256((size_t)Etot * 2);
  ull* w4      = (ull*)(w + off);   off += align256((size_t)Etot * 8);

  int nb4 = (N + 3) / 4;
  int rowblocks = (N + 63) / 64;             // 782
  int pblocks = (Etot + 2047) / 2048;        // 806
  int fblocks = (N + 15) / 16;               // 3125

  setup_kernel<<<104, 256, 0, stream>>>(W1, W2, W1b, W2b, gcursor, poolrep);
  gemm1_partition<<<rowblocks + pblocks, 256, 0, stream>>>(
      x, W1b, h1b8, as1, ad1, att_src1, att_dst1, N, rowblocks,
      ei_src, ei_dst, gcursor, pairs, E, Etot);
  bucket_csr<<<NBUCK, 512, 0, stream>>>(pairs, gcursor,
                                        (const float4*)as1, (const float4*)ad1,
                                        src16, w4, row_ptr, N, Etot);
  agg1_gemm2<<<fblocks, 256, 0, stream>>>(h1b8, src16, w4, row_ptr, b1, W2b,
                                          att_src2, att_dst2, h2b8, as2, ad2, N);
  agg2_pool<<<nb4, 256, 0, stream>>>(h2b8, as2, ad2, row_ptr, src16, b2, poolrep, N);
  head_kernel<<<1, 64, 0, stream>>>(poolrep, Wc, bc, out, 1.0f / (float)N);
}

// Round 19
// 180.555 us; speedup vs baseline: 1.0616x; 1.0013x over previous
//
#include <hip/hip_runtime.h>
#include <cstdint>
#include <cstddef>

#define NEG_SLOPE 0.2f
#define F_IN 128
#define C1 256      // HEADS*HID layer-1 width
#define HID 64
#define HEADS 4
#define LOG2E 1.4426950408889634f
#define NBUCK 392   // ceil(50000/128)
#define BCAP 5120   // per-bucket capacity (mean 4224, sigma ~65)

typedef __attribute__((ext_vector_type(8))) short bf16x8;
typedef __attribute__((ext_vector_type(4))) float f32x4;
typedef __attribute__((ext_vector_type(2))) float f32x2;
typedef unsigned long long ull;

__device__ __forceinline__ float wave_reduce_sum(float v) {
#pragma unroll
  for (int off = 32; off > 0; off >>= 1) v += __shfl_down(v, off);
  return v;
}

__device__ __forceinline__ unsigned short f2bf(float f) {
  union { float f; unsigned int u; } v; v.f = f;
  unsigned int u = v.u;
  unsigned int r = (u + 0x7fffu + ((u >> 16) & 1u)) >> 16;  // RNE
  return (unsigned short)r;
}

__device__ __forceinline__ unsigned char f2fp8(float f) {
  int p = __builtin_amdgcn_cvt_pk_fp8_f32(f, f, 0, false);  // OCP e4m3fn
  return (unsigned char)(p & 0xff);
}

// ---------------- setup: zero gcursor/poolrep + weight pre-pack (merged) --------
__global__ __launch_bounds__(256) void setup_kernel(const float* __restrict__ W1,
                                                    const float* __restrict__ W2,
                                                    unsigned short* __restrict__ W1b,
                                                    unsigned short* __restrict__ W2b,
                                                    int* __restrict__ gcursor,
                                                    float* __restrict__ poolrep) {
  const int TOT = 512 + 4096 + 32768 + 16384;
  for (int idx = threadIdx.x + blockIdx.x * 256; idx < TOT; idx += 256 * gridDim.x) {
    if (idx < 512) {
      gcursor[idx] = 0;
    } else if (idx < 512 + 4096) {
      poolrep[idx - 512] = 0.f;
    } else if (idx < 512 + 4096 + 32768) {
      int o = idx - (512 + 4096);
      int head = o >> 13, ks = (o >> 11) & 3, nt = (o >> 9) & 3;
      int lane = (o >> 3) & 63, j = o & 7;
      int k = ks * 32 + (lane >> 4) * 8 + j;
      int c = head * 64 + nt * 16 + (lane & 15);
      W1b[o] = f2bf(W1[k * 256 + c]);
    } else {
      int o = idx - (512 + 4096 + 32768);
      int ks = o >> 11, nt = (o >> 9) & 3, lane = (o >> 3) & 63, j = o & 7;
      int k = ks * 32 + (lane >> 4) * 8 + j;
      int c = nt * 16 + (lane & 15);
      W2b[o] = f2bf(W2[k * 64 + c]);
    }
  }
}

// ---------------- fat kernel: GEMM1 (blocks < rowblocks) + edge partition ------
__global__ __launch_bounds__(256) void gemm1_partition(const float* __restrict__ Af,
                                                       const unsigned short* __restrict__ Wb,
                                                       unsigned char* __restrict__ H8,
                                                       float* __restrict__ as_out,
                                                       float* __restrict__ ad_out,
                                                       const float* __restrict__ att_s,
                                                       const float* __restrict__ att_d,
                                                       int M, int rowblocks,
                                                       const int* __restrict__ esrc,
                                                       const int* __restrict__ edst,
                                                       int* __restrict__ gcursor,
                                                       unsigned* __restrict__ pairs,
                                                       int E, int Etot) {
  __shared__ int hist[512];
  __shared__ int base[512];
  if (blockIdx.x < rowblocks) {
    // ---- GEMM1: fp32 A -> bf16 MFMA, fp8 h-store, all heads ----
    constexpr int KSTEPS = 4, NH = HEADS, K = 128, N = 256;
    const int lane = threadIdx.x & 63, wid = threadIdx.x >> 6;
    const int rowbase = blockIdx.x * 64 + wid * 16;
    const int g = lane >> 4, li = lane & 15;
    int r_a = rowbase + li;
    if (r_a > M - 1) r_a = M - 1;

    f32x4 acc[NH][4];
#pragma unroll
    for (int h = 0; h < NH; h++)
#pragma unroll
      for (int nt = 0; nt < 4; nt++) {
        acc[h][nt][0] = 0.f; acc[h][nt][1] = 0.f; acc[h][nt][2] = 0.f; acc[h][nt][3] = 0.f;
      }

#pragma unroll
    for (int ks = 0; ks < KSTEPS; ks++) {
      bf16x8 a;
      const float* p = Af + (size_t)r_a * K + ks * 32 + g * 8;
      float4 v0 = *(const float4*)p, v1 = *(const float4*)(p + 4);
      a[0] = (short)f2bf(v0.x); a[1] = (short)f2bf(v0.y);
      a[2] = (short)f2bf(v0.z); a[3] = (short)f2bf(v0.w);
      a[4] = (short)f2bf(v1.x); a[5] = (short)f2bf(v1.y);
      a[6] = (short)f2bf(v1.z); a[7] = (short)f2bf(v1.w);
#pragma unroll
      for (int h = 0; h < NH; h++)
#pragma unroll
        for (int nt = 0; nt < 4; nt++) {
          bf16x8 b = *(const bf16x8*)(Wb + ((size_t)((h * KSTEPS + ks) * 4 + nt) * 64 + lane) * 8);
          acc[h][nt] = __builtin_amdgcn_mfma_f32_16x16x32_bf16(a, b, acc[h][nt], 0, 0, 0);
        }
    }

#pragma unroll
    for (int h = 0; h < NH; h++) {
      float asum[4] = {0.f, 0.f, 0.f, 0.f}, dsum[4] = {0.f, 0.f, 0.f, 0.f};
#pragma unroll
      for (int nt = 0; nt < 4; nt++) {
        float ws = att_s[h * 64 + nt * 16 + li];
        float wd = att_d[h * 64 + nt * 16 + li];
#pragma unroll
        for (int r = 0; r < 4; r++) { asum[r] += acc[h][nt][r] * ws; dsum[r] += acc[h][nt][r] * wd; }
      }
#pragma unroll
      for (int r = 0; r < 4; r++) {
#pragma unroll
        for (int m = 1; m < 16; m <<= 1) {
          asum[r] += __shfl_xor(asum[r], m);
          dsum[r] += __shfl_xor(dsum[r], m);
        }
      }
#pragma unroll
      for (int r = 0; r < 4; r++) {
        int gr = rowbase + g * 4 + r;
        if (gr < M) {
#pragma unroll
          for (int nt = 0; nt < 4; nt++)
            H8[(size_t)gr * N + h * 64 + nt * 16 + li] = f2fp8(acc[h][nt][r]);
          if (li == 0) {
            as_out[(size_t)gr * NH + h] = asum[r] * LOG2E;
            ad_out[(size_t)gr * NH + h] = dsum[r] * LOG2E;
          }
        }
      }
    }
  } else {
    // ---- partition: packed 4B pairs into 392 coarse buckets (dst>>7) ----
    const int tid = threadIdx.x;
    const int e0 = (blockIdx.x - rowblocks) * 2048;
    hist[tid] = 0; hist[tid + 256] = 0;
    __syncthreads();
    int d8[8], rk8[8], bk8[8];
#pragma unroll
    for (int j = 0; j < 8; j++) {
      int e = e0 + tid * 8 + j;
      d8[j] = -1;
      if (e < Etot) {
        int d = (e < E) ? edst[e] : (e - E);
        d8[j] = d;
        bk8[j] = d >> 7;
        rk8[j] = atomicAdd(&hist[bk8[j]], 1);
      }
    }
    __syncthreads();
    if (hist[tid] > 0) base[tid] = atomicAdd(&gcursor[tid], hist[tid]);
    if (hist[tid + 256] > 0) base[tid + 256] = atomicAdd(&gcursor[tid + 256], hist[tid + 256]);
    __syncthreads();
#pragma unroll
    for (int j = 0; j < 8; j++) {
      int e = e0 + tid * 8 + j;
      if (e < Etot) {
        int s = (e < E) ? esrc[e] : (e - E);
        pairs[(size_t)bk8[j] * BCAP + base[bk8[j]] + rk8[j]] =
            (unsigned)s | ((unsigned)(d8[j] & 127) << 16);
      }
    }
  }
}

// per-bucket CSR (128 dsts) + fused edge weights; computes its own bucket prefix.
__global__ __launch_bounds__(512) void bucket_csr(const unsigned* __restrict__ pairs,
                                                  const int* __restrict__ gcursor,
                                                  const float4* __restrict__ as1,
                                                  const float4* __restrict__ ad1,
                                                  unsigned short* __restrict__ src16,
                                                  ull* __restrict__ w4,
                                                  int* __restrict__ row_ptr,
                                                  int N, int Etot) {
  __shared__ int hist[128], offs[128], cnt2[128], gpre[512];
  const int b = blockIdx.x;
  const int tid = threadIdx.x;
  if (tid < 128) { hist[tid] = 0; cnt2[tid] = 0; }
  gpre[tid] = (tid < NBUCK) ? gcursor[tid] : 0;
  __syncthreads();
  // inclusive scan over 512 (bucket counts)
  for (int off = 1; off < 512; off <<= 1) {
    int t = (tid >= off) ? gpre[tid - off] : 0;
    __syncthreads();
    gpre[tid] += t;
    __syncthreads();
  }
  const int cnt = gcursor[b];
  const int gbase = (b == 0) ? 0 : gpre[b - 1];
  const unsigned* bp = pairs + (size_t)b * BCAP;
  if (b == 0 && tid == 0) row_ptr[N] = Etot;

  for (int i = tid; i < cnt; i += 512) {
    unsigned p = bp[i];
    atomicAdd(&hist[p >> 16], 1);
  }
  __syncthreads();
  if (tid < 128) offs[tid] = hist[tid];
  __syncthreads();
  for (int off = 1; off < 128; off <<= 1) {
    int t = 0;
    if (tid < 128 && tid >= off) t = offs[tid - off];
    __syncthreads();
    if (tid < 128) offs[tid] += t;
    __syncthreads();
  }
  if (tid < 128) {
    int node = b * 128 + tid;
    if (node < N) row_ptr[node] = gbase + offs[tid] - hist[tid];
  }
  __syncthreads();
  for (int i = tid; i < cnt; i += 512) {
    unsigned p = bp[i];
    int lo = (int)(p >> 16);
    int src = (int)(p & 0xffffu);
    int rank = atomicAdd(&cnt2[lo], 1);
    int pos = gbase + offs[lo] - hist[lo] + rank;
    float4 a = as1[src], dd = ad1[b * 128 + lo];
    float s0 = a.x + dd.x, s1 = a.y + dd.y, s2 = a.z + dd.z, s3 = a.w + dd.w;
    float w0 = exp2f(fmaxf(s0, NEG_SLOPE * s0));
    float w1 = exp2f(fmaxf(s1, NEG_SLOPE * s1));
    float w2 = exp2f(fmaxf(s2, NEG_SLOPE * s2));
    float w3 = exp2f(fmaxf(s3, NEG_SLOPE * s3));
    unsigned w01 = (unsigned)f2bf(w0) | ((unsigned)f2bf(w1) << 16);
    unsigned w23 = (unsigned)f2bf(w2) | ((unsigned)f2bf(w3) << 16);
    src16[pos] = (unsigned short)src;
    w4[pos] = (ull)w01 | ((ull)w23 << 32);
  }
}

// ---------------- fused: layer-1 aggregate + GEMM2 + alpha2 dots ----------------
__global__ __launch_bounds__(256) void agg1_gemm2(const unsigned char* __restrict__ H8,
                                                  const unsigned short* __restrict__ src16,
                                                  const ull* __restrict__ w4,
                                                  const int* __restrict__ row_ptr,
                                                  const float* __restrict__ b1,
                                                  const unsigned short* __restrict__ W2b,
                                                  const float* __restrict__ att_s2,
                                                  const float* __restrict__ att_d2,
                                                  unsigned char* __restrict__ H2,
                                                  float* __restrict__ as2,
                                                  float* __restrict__ ad2, int n) {
  __shared__ unsigned char lds_h[16 * 512];   // 16 rows x 256 bf16, swizzled
  __shared__ float pA[4][16], pD[4][16];
  const int tid = threadIdx.x;
  const int l = tid & 63, w = tid >> 6;
  const int dbase = blockIdx.x * 16;
  const int hh = l >> 4;
  const int shamt = (hh & 1) ? 0 : 16;
  const bool lowpair = hh < 2;
  const float4 bb = *(const float4*)(b1 + l * 4);

  // preload all row bounds for this wave's 4 dsts (5 scalar loads, issued together)
  const int dw = dbase + w * 4;
  int bnd[5];
#pragma unroll
  for (int j = 0; j < 5; j++) bnd[j] = row_ptr[min(dw + j, n)];

#define WSEL(wv) __uint_as_float((((lowpair) ? (unsigned)(wv) : (unsigned)((wv) >> 32)) << shamt) & 0xffff0000u)
#define ACCUM(wgt, u8)                                                     \
  {                                                                        \
    f32x2 lo_ = __builtin_amdgcn_cvt_pk_f32_fp8((int)(u8), false);         \
    f32x2 hi_ = __builtin_amdgcn_cvt_pk_f32_fp8((int)(u8), true);          \
    accA += lo_ * (wgt); accB += hi_ * (wgt);                              \
    denom += (wgt);                                                        \
  }
  for (int i = 0; i < 4; i++) {
    int dloc = w * 4 + i;
    int d = dbase + dloc;
    bool active = d < n;
    f32x2 accA = {0.f, 0.f}, accB = {0.f, 0.f};
    float denom = 0.f;
    if (active) {
      int e0 = __builtin_amdgcn_readfirstlane(bnd[i]);
      int e1 = __builtin_amdgcn_readfirstlane(bnd[i + 1]);
      const int nbatch = (e1 - e0) >> 3;   // counted batch loop (8 edges/batch)
      int e = e0;
#pragma unroll 2
      for (int bt = 0; bt < nbatch; bt++) {
        int eb = e0 + bt * 8;
        unsigned s0 = src16[eb],     s1 = src16[eb + 1];
        unsigned s2 = src16[eb + 2], s3 = src16[eb + 3];
        unsigned s4 = src16[eb + 4], s5 = src16[eb + 5];
        unsigned s6 = src16[eb + 6], s7 = src16[eb + 7];
        ull wv0 = w4[eb],     wv1 = w4[eb + 1], wv2 = w4[eb + 2], wv3 = w4[eb + 3];
        ull wv4 = w4[eb + 4], wv5 = w4[eb + 5], wv6 = w4[eb + 6], wv7 = w4[eb + 7];
        unsigned u0 = *(const unsigned*)(H8 + (size_t)s0 * C1 + l * 4);
        unsigned u1 = *(const unsigned*)(H8 + (size_t)s1 * C1 + l * 4);
        unsigned u2 = *(const unsigned*)(H8 + (size_t)s2 * C1 + l * 4);
        unsigned u3 = *(const unsigned*)(H8 + (size_t)s3 * C1 + l * 4);
        unsigned u4 = *(const unsigned*)(H8 + (size_t)s4 * C1 + l * 4);
        unsigned u5 = *(const unsigned*)(H8 + (size_t)s5 * C1 + l * 4);
        unsigned u6 = *(const unsigned*)(H8 + (size_t)s6 * C1 + l * 4);
        unsigned u7 = *(const unsigned*)(H8 + (size_t)s7 * C1 + l * 4);
        float w0 = WSEL(wv0), w1 = WSEL(wv1), w2 = WSEL(wv2), w3 = WSEL(wv3);
        float w4_ = WSEL(wv4), w5 = WSEL(wv5), w6 = WSEL(wv6), w7 = WSEL(wv7);
        ACCUM(w0, u0) ACCUM(w1, u1) ACCUM(w2, u2) ACCUM(w3, u3)
        ACCUM(w4_, u4) ACCUM(w5, u5) ACCUM(w6, u6) ACCUM(w7, u7)
      }
      e = e0 + nbatch * 8;
      for (; e < e1; e++) {
        unsigned s0 = src16[e];
        ull wv = w4[e];
        unsigned u = *(const unsigned*)(H8 + (size_t)s0 * C1 + l * 4);
        float wq = WSEL(wv);
        ACCUM(wq, u)
      }
    }
    float inv = 1.f / (denom + 1e-16f);
    float4 o;
    o.x = accA[0] * inv + bb.x; o.y = accA[1] * inv + bb.y;
    o.z = accB[0] * inv + bb.z; o.w = accB[1] * inv + bb.w;
    o.x = o.x > 0.f ? o.x : (__expf(o.x) - 1.f);
    o.y = o.y > 0.f ? o.y : (__expf(o.y) - 1.f);
    o.z = o.z > 0.f ? o.z : (__expf(o.z) - 1.f);
    o.w = o.w > 0.f ? o.w : (__expf(o.w) - 1.f);
    if (!active) { o.x = 0.f; o.y = 0.f; o.z = 0.f; o.w = 0.f; }
    uint2 pk;
    pk.x = (unsigned int)f2bf(o.x) | ((unsigned int)f2bf(o.y) << 16);
    pk.y = (unsigned int)f2bf(o.z) | ((unsigned int)f2bf(o.w) << 16);
    unsigned byte = (unsigned)(l * 8) ^ ((unsigned)(dloc & 7) << 4);
    *(uint2*)(lds_h + dloc * 512 + byte) = pk;
  }
#undef ACCUM
#undef WSEL
  __syncthreads();

  const int li2 = l & 15, g2 = l >> 4;
  f32x4 acc2;
  acc2[0] = 0.f; acc2[1] = 0.f; acc2[2] = 0.f; acc2[3] = 0.f;
#pragma unroll
  for (int ks = 0; ks < 8; ks++) {
    unsigned byte = (unsigned)((ks * 32 + g2 * 8) * 2) ^ ((unsigned)(li2 & 7) << 4);
    bf16x8 a = *(const bf16x8*)(lds_h + li2 * 512 + byte);
    bf16x8 b = *(const bf16x8*)(W2b + ((size_t)(ks * 4 + w) * 64 + l) * 8);
    acc2 = __builtin_amdgcn_mfma_f32_16x16x32_bf16(a, b, acc2, 0, 0, 0);
  }

  float ws = att_s2[w * 16 + li2], wd = att_d2[w * 16 + li2];
  float asum[4], dsum[4];
#pragma unroll
  for (int r = 0; r < 4; r++) { asum[r] = acc2[r] * ws; dsum[r] = acc2[r] * wd; }
#pragma unroll
  for (int r = 0; r < 4; r++) {
#pragma unroll
    for (int m = 1; m < 16; m <<= 1) {
      asum[r] += __shfl_xor(asum[r], m);
      dsum[r] += __shfl_xor(dsum[r], m);
    }
  }
#pragma unroll
  for (int r = 0; r < 4; r++) {
    int row = g2 * 4 + r;
    int d2 = dbase + row;
    if (d2 < n) H2[(size_t)d2 * HID + w * 16 + li2] = f2fp8(acc2[r]);
    if (li2 == 0) { pA[w][row] = asum[r]; pD[w][row] = dsum[r]; }
  }
  __syncthreads();
  if (tid < 16) {
    int d2 = dbase + tid;
    if (d2 < n) as2[d2] = (pA[0][tid] + pA[1][tid] + pA[2][tid] + pA[3][tid]) * LOG2E;
  } else if (tid < 32) {
    int row = tid - 16;
    int d2 = dbase + row;
    if (d2 < n) ad2[d2] = (pD[0][row] + pD[1][row] + pD[2][row] + pD[3][row]) * LOG2E;
  }
}

// ---------------- layer-2 aggregate (fp8 gather, src16 stream) + mean pool ------
__global__ __launch_bounds__(256) void agg2_pool(const unsigned char* __restrict__ H2,
                                                 const float* __restrict__ as_,
                                                 const float* __restrict__ ad_,
                                                 const int* __restrict__ row_ptr,
                                                 const unsigned short* __restrict__ src16,
                                                 const float* __restrict__ b2,
                                                 float* __restrict__ poolrep, int n) {
  __shared__ float lds[4][64];
  int wid = threadIdx.x >> 6;
  int d = blockIdx.x * 4 + wid;
  int l = threadIdx.x & 63, q = l >> 4, li = l & 15;
  float ad = ad_[d];
  int e0 = __builtin_amdgcn_readfirstlane(row_ptr[d]);
  int e1 = __builtin_amdgcn_readfirstlane(row_ptr[d + 1]);
  f32x2 accA = {0.f, 0.f}, accB = {0.f, 0.f};
  float denom = 0.f;
  int e = e0 + q;
  for (; e + 4 < e1; e += 8) {
    int sa = (int)src16[e];
    int sb = (int)src16[e + 4];
    float sca = as_[sa] + ad, scb = as_[sb] + ad;
    float wa = exp2f(fmaxf(sca, NEG_SLOPE * sca));
    float wb = exp2f(fmaxf(scb, NEG_SLOPE * scb));
    unsigned ua = *(const unsigned*)(H2 + (size_t)sa * HID + li * 4);
    unsigned ub = *(const unsigned*)(H2 + (size_t)sb * HID + li * 4);
    f32x2 loa = __builtin_amdgcn_cvt_pk_f32_fp8((int)ua, false);
    f32x2 hia = __builtin_amdgcn_cvt_pk_f32_fp8((int)ua, true);
    f32x2 lob = __builtin_amdgcn_cvt_pk_f32_fp8((int)ub, false);
    f32x2 hib = __builtin_amdgcn_cvt_pk_f32_fp8((int)ub, true);
    accA += loa * wa; accB += hia * wa;
    accA += lob * wb; accB += hib * wb;
    denom += wa + wb;
  }
  for (; e < e1; e += 4) {
    int s = (int)src16[e];
    float sc = as_[s] + ad;
    float w = exp2f(fmaxf(sc, NEG_SLOPE * sc));
    denom += w;
    unsigned u = *(const unsigned*)(H2 + (size_t)s * HID + li * 4);
    f32x2 lo_ = __builtin_amdgcn_cvt_pk_f32_fp8((int)u, false);
    f32x2 hi_ = __builtin_amdgcn_cvt_pk_f32_fp8((int)u, true);
    accA += lo_ * w; accB += hi_ * w;
  }
#pragma unroll
  for (int m = 16; m <= 32; m <<= 1) {
    accA[0] += __shfl_xor(accA[0], m); accA[1] += __shfl_xor(accA[1], m);
    accB[0] += __shfl_xor(accB[0], m); accB[1] += __shfl_xor(accB[1], m);
    denom += __shfl_xor(denom, m);
  }
  if (q == 0) {
    float inv = 1.f / (denom + 1e-16f);
    float o[4] = {accA[0] * inv + b2[li * 4], accA[1] * inv + b2[li * 4 + 1],
                  accB[0] * inv + b2[li * 4 + 2], accB[1] * inv + b2[li * 4 + 3]};
#pragma unroll
    for (int j = 0; j < 4; j++) {
      float v = o[j];
      lds[wid][li * 4 + j] = v > 0.f ? v : (__expf(v) - 1.f);
    }
  }
  __syncthreads();
  if (threadIdx.x < 64) {
    int c = threadIdx.x;
    float v = lds[0][c] + lds[1][c] + lds[2][c] + lds[3][c];
    atomicAdd(&poolrep[(blockIdx.x & 63) * 64 + c], v);
  }
}

__global__ __launch_bounds__(64) void head_kernel(const float* __restrict__ poolrep,
                                                  const float* __restrict__ Wc,
                                                  const float* __restrict__ bc,
                                                  float* __restrict__ out, float inv_n) {
  int l = threadIdx.x;
  float p = 0.f;
  for (int k = 0; k < 64; k++) p += poolrep[k * 64 + l];
  p *= inv_n;
  float o0 = wave_reduce_sum(p * Wc[l * 2 + 0]);
  float o1 = wave_reduce_sum(p * Wc[l * 2 + 1]);
  if (l == 0) { out[0] = o0 + bc[0]; out[1] = o1 + bc[1]; }
}

// ---------------- host ----------------
static inline size_t align256(size_t x) { return (x + 255) & ~(size_t)255; }

extern "C" void kernel_launch(void* const* d_in, const int* in_sizes, int n_in,
                              void* d_out, int out_size, void* d_ws, size_t ws_size,
                              hipStream_t stream) {
  const float* x        = (const float*)d_in[0];
  const int*   ei       = (const int*)d_in[1];
  const float* W1       = (const float*)d_in[2];
  const float* att_src1 = (const float*)d_in[3];
  const float* att_dst1 = (const float*)d_in[4];
  const float* b1       = (const float*)d_in[5];
  const float* W2       = (const float*)d_in[6];
  const float* att_src2 = (const float*)d_in[7];
  const float* att_dst2 = (const float*)d_in[8];
  const float* b2       = (const float*)d_in[9];
  const float* Wc       = (const float*)d_in[10];
  const float* bc       = (const float*)d_in[11];
  float* out = (float*)d_out;

  const int N = in_sizes[0] / F_IN;          // 50000
  const int E = in_sizes[1] / 2;             // 1,600,000
  const int Etot = E + N;                    // + self loops
  const int* ei_src = ei;
  const int* ei_dst = ei + E;

  // workspace layout (~46 MB)
  char* w = (char*)d_ws;
  size_t off = 0;
  unsigned char* h1b8 = (unsigned char*)(w + off); off += align256((size_t)N * C1);   // 12.8MB fp8
  unsigned char* h2b8 = (unsigned char*)(w + off); off += align256((size_t)N * HID);  // 3.2MB fp8
  float* as1   = (float*)(w + off); off += align256((size_t)N * HEADS * 4);
  float* ad1   = (float*)(w + off); off += align256((size_t)N * HEADS * 4);
  float* as2   = (float*)(w + off); off += align256((size_t)N * 4);
  float* ad2   = (float*)(w + off); off += align256((size_t)N * 4);
  int* row_ptr = (int*)(w + off);   off += align256((size_t)(N + 1) * 4);
  int* gcursor = (int*)(w + off);   off += align256(512 * 4);
  float* poolrep = (float*)(w + off); off += align256(64 * 64 * 4);
  unsigned short* W1b = (unsigned short*)(w + off); off += align256(32768 * 2);
  unsigned short* W2b = (unsigned short*)(w + off); off += align256(16384 * 2);
  unsigned* pairs = (unsigned*)(w + off); off += align256((size_t)NBUCK * BCAP * 4);  // 8MB
  unsigned short* src16 = (unsigned short*)(w + off); off += align256((size_t)Etot * 2);
  ull* w4      = (ull*)(w + off);   off += align256((size_t)Etot * 8);

  int nb4 = (N + 3) / 4;
  int rowblocks = (N + 63) / 64;             // 782
  int pblocks = (Etot + 2047) / 2048;        // 806
  int fblocks = (N + 15) / 16;               // 3125

  setup_kernel<<<104, 256, 0, stream>>>(W1, W2, W1b, W2b, gcursor, poolrep);
  gemm1_partition<<<rowblocks + pblocks, 256, 0, stream>>>(
      x, W1b, h1b8, as1, ad1, att_src1, att_dst1, N, rowblocks,
      ei_src, ei_dst, gcursor, pairs, E, Etot);
  bucket_csr<<<NBUCK, 512, 0, stream>>>(pairs, gcursor,
                                        (const float4*)as1, (const float4*)ad1,
                                        src16, w4, row_ptr, N, Etot);
  agg1_gemm2<<<fblocks, 256, 0, stream>>>(h1b8, src16, w4, row_ptr, b1, W2b,
                                          att_src2, att_dst2, h2b8, as2, ad2, N);
  agg2_pool<<<nb4, 256, 0, stream>>>(h2b8, as2, ad2, row_ptr, src16, b2, poolrep, N);
  head_kernel<<<1, 64, 0, stream>>>(poolrep, Wc, bc, out, 1.0f / (float)N);
}